// Round 1
// baseline (3145.133 us; speedup 1.0000x reference)
//
#include <hip/hip_runtime.h>

// Problem: B=32, C=256, H=W=64, N=4096, R=16.
// out = conv1x1(w_w, softmax(x@x^T * C^-0.5 + w1@w2^T) @ conv3x3(x_mid, g_w))
// Folded: out = (w_w @ attn) @ value   (1x1 conv commutes with attention matmul)

#define NB 32
#define NC 256
#define NPIX 4096   // 64*64

// ---------------- random_map = w1 @ w2^T  [256,256] ----------------
__global__ __launch_bounds__(256) void rm_kernel(const float* __restrict__ w1,
                                                 const float* __restrict__ w2,
                                                 float* __restrict__ rm) {
    int idx = blockIdx.x * 256 + threadIdx.x;   // 65536 total
    int c = idx >> 8, d = idx & 255;
    float s = 0.f;
#pragma unroll
    for (int r = 0; r < 16; r++) s += w1[c * 16 + r] * w2[d * 16 + r];
    rm[idx] = s;
}

// ---------------- conv3x3 SAME: value[b,co,h*64+w] ----------------
// Implicit im2col GEMM: 64co x 64px (one image row) tile, 4x4 per thread.
__global__ __launch_bounds__(256) void conv3x3_kernel(const float* __restrict__ x,
                                                      const float* __restrict__ w,
                                                      float* __restrict__ out) {
    const int h   = blockIdx.x;        // 0..63 (one output row per block)
    const int co0 = blockIdx.y * 64;   // 0..3
    const int b   = blockIdx.z;        // 0..31
    __shared__ float Aw[8][9][68];     // [ci][tap][co], pad 68 to break conflicts
    __shared__ float Bx[8][3][68];     // [ci][kh row][1+w], halo at [0] and [65]
    const int tid = threadIdx.x;
    const int tx = tid & 15, ty = tid >> 4;
    float acc[4][4] = {};

    for (int ci0 = 0; ci0 < 256; ci0 += 8) {
        __syncthreads();
        // stage weights: g_w[co0+co, ci0..ci0+7, :, :] -> Aw  (contiguous 72-float runs)
        for (int i = tid; i < 64 * 72; i += 256) {
            int co = i / 72, j = i - co * 72;      // j = ci_local*9 + tap
            Aw[j / 9][j % 9][co] = w[(size_t)(co0 + co) * 2304 + ci0 * 9 + j];
        }
        // stage input rows h-1..h+1 for 8 channels, zero-padded halo
        for (int i = tid; i < 8 * 3 * 64; i += 256) {
            int ci = i / 192, rem = i - ci * 192, r = rem >> 6, ww = rem & 63;
            int hin = h - 1 + r;
            float v = 0.f;
            if ((unsigned)hin < 64u)
                v = x[(((size_t)(b * 256 + ci0 + ci)) * 64 + hin) * 64 + ww];
            Bx[ci][r][1 + ww] = v;
        }
        if (tid < 24) { int ci = tid / 3, r = tid - ci * 3; Bx[ci][r][0] = 0.f; Bx[ci][r][65] = 0.f; }
        __syncthreads();

#pragma unroll
        for (int ci = 0; ci < 8; ci++) {
#pragma unroll
            for (int kh = 0; kh < 3; kh++) {
                float bseg[6];
                float4 b4 = *(float4*)&Bx[ci][kh][tx * 4];
                bseg[0] = b4.x; bseg[1] = b4.y; bseg[2] = b4.z; bseg[3] = b4.w;
                float2 b2 = *(float2*)&Bx[ci][kh][tx * 4 + 4];
                bseg[4] = b2.x; bseg[5] = b2.y;
#pragma unroll
                for (int kw = 0; kw < 3; kw++) {
                    float4 a = *(float4*)&Aw[ci][kh * 3 + kw][ty * 4];
                    float av[4] = {a.x, a.y, a.z, a.w};
#pragma unroll
                    for (int i2 = 0; i2 < 4; i2++)
#pragma unroll
                        for (int j2 = 0; j2 < 4; j2++)
                            acc[i2][j2] += av[i2] * bseg[j2 + kw];
                }
            }
        }
    }
#pragma unroll
    for (int i2 = 0; i2 < 4; i2++) {
        float4 o = make_float4(acc[i2][0], acc[i2][1], acc[i2][2], acc[i2][3]);
        *(float4*)&out[((size_t)(b * 256 + co0 + ty * 4 + i2)) * 4096 + h * 64 + tx * 4] = o;
    }
}

// ---------------- generic batched fp32 GEMM, 64x64 tile, 4x4/thread ----------
// BT=0: C[m,n] = sum_k A[m,k] * B[k,n]    (B row-major [K,N], ldB)
// BT=1: C[m,n] = sum_k A[m,k] * B[n,k]    (B row-major [N,K], ldB)
template <int BT>
__global__ __launch_bounds__(256) void gemm64(const float* __restrict__ A,
                                              const float* __restrict__ B,
                                              float* __restrict__ C, int K,
                                              long sA, long sB, long sC,
                                              int ldA, int ldB, int ldC, int tilesN) {
    const int m0 = (blockIdx.x / tilesN) * 64;
    const int n0 = (blockIdx.x % tilesN) * 64;
    A += (size_t)blockIdx.y * sA;
    B += (size_t)blockIdx.y * sB;
    C += (size_t)blockIdx.y * sC;
    __shared__ float As[16][68], Bs[16][68];   // [k][m] / [k][n], padded
    const int tid = threadIdx.x;
    const int tx = tid & 15, ty = tid >> 4;
    const int mm = tid >> 2, kk4 = (tid & 3) * 4;
    float acc[4][4] = {};

    for (int k0 = 0; k0 < K; k0 += 16) {
        __syncthreads();
        {
            float4 a = *(const float4*)&A[(size_t)(m0 + mm) * ldA + k0 + kk4];
            As[kk4 + 0][mm] = a.x; As[kk4 + 1][mm] = a.y;
            As[kk4 + 2][mm] = a.z; As[kk4 + 3][mm] = a.w;
        }
        if (BT) {
            float4 bv = *(const float4*)&B[(size_t)(n0 + mm) * ldB + k0 + kk4];
            Bs[kk4 + 0][mm] = bv.x; Bs[kk4 + 1][mm] = bv.y;
            Bs[kk4 + 2][mm] = bv.z; Bs[kk4 + 3][mm] = bv.w;
        } else {
            int bk = tid >> 4, bn = (tid & 15) * 4;
            *(float4*)&Bs[bk][bn] = *(const float4*)&B[(size_t)(k0 + bk) * ldB + n0 + bn];
        }
        __syncthreads();
#pragma unroll
        for (int kk = 0; kk < 16; kk++) {
            float4 a = *(float4*)&As[kk][ty * 4];
            float4 bv = *(float4*)&Bs[kk][tx * 4];
            float av[4] = {a.x, a.y, a.z, a.w};
            float bb[4] = {bv.x, bv.y, bv.z, bv.w};
#pragma unroll
            for (int i = 0; i < 4; i++)
#pragma unroll
                for (int j = 0; j < 4; j++) acc[i][j] += av[i] * bb[j];
        }
    }
#pragma unroll
    for (int i = 0; i < 4; i++) {
        float4 o = make_float4(acc[i][0], acc[i][1], acc[i][2], acc[i][3]);
        *(float4*)&C[(size_t)(m0 + ty * 4 + i) * ldC + n0 + tx * 4] = o;
    }
}

// ---------------- softmax over last dim (256) with scale + bias -------------
// sim[row][d] <- softmax(sim*0.0625 + rm[c][d]); one wave per row.
__global__ __launch_bounds__(256) void softmax_kernel(float* __restrict__ sim,
                                                      const float* __restrict__ rm) {
    int row  = blockIdx.x * 4 + (threadIdx.x >> 6);  // 8192 rows
    int lane = threadIdx.x & 63;
    int c = row & 255;
    float4 v = *(float4*)&sim[(size_t)row * 256 + lane * 4];
    const float4 bias = *(const float4*)&rm[c * 256 + lane * 4];
    v.x = v.x * 0.0625f + bias.x;
    v.y = v.y * 0.0625f + bias.y;
    v.z = v.z * 0.0625f + bias.z;
    v.w = v.w * 0.0625f + bias.w;
    float m = fmaxf(fmaxf(v.x, v.y), fmaxf(v.z, v.w));
#pragma unroll
    for (int off = 32; off > 0; off >>= 1) m = fmaxf(m, __shfl_xor(m, off, 64));
    float e0 = __expf(v.x - m), e1 = __expf(v.y - m);
    float e2 = __expf(v.z - m), e3 = __expf(v.w - m);
    float s = e0 + e1 + e2 + e3;
#pragma unroll
    for (int off = 32; off > 0; off >>= 1) s += __shfl_xor(s, off, 64);
    float inv = 1.f / s;
    float4 o = make_float4(e0 * inv, e1 * inv, e2 * inv, e3 * inv);
    *(float4*)&sim[(size_t)row * 256 + lane * 4] = o;
}

extern "C" void kernel_launch(void* const* d_in, const int* in_sizes, int n_in,
                              void* d_out, int out_size, void* d_ws, size_t ws_size,
                              hipStream_t stream) {
    const float* x     = (const float*)d_in[0];
    const float* x_mid = (const float*)d_in[1];
    const float* g_w   = (const float*)d_in[2];
    const float* w_w   = (const float*)d_in[3];  // [C,C,1,1] == [co,ci]
    const float* w1    = (const float*)d_in[4];
    const float* w2    = (const float*)d_in[5];
    float* out = (float*)d_out;

    char* ws = (char*)d_ws;
    float* value = (float*)ws;                                  // [32,256,4096]
    float* sim   = (float*)(ws + (size_t)NB * NC * NPIX * 4);   // [32,256,256]
    float* attn2 = sim + (size_t)NB * NC * NC;                  // [32,256,256]
    float* rm    = attn2 + (size_t)NB * NC * NC;                // [256,256]

    // random_map (independent)
    rm_kernel<<<256, 256, 0, stream>>>(w1, w2, rm);
    // value = conv3x3(x_mid, g_w)
    conv3x3_kernel<<<dim3(64, 4, 32), 256, 0, stream>>>(x_mid, g_w, value);
    // sim = x @ x^T   (NT GEMM, M=N=256, K=4096)
    gemm64<1><<<dim3(16, 32), 256, 0, stream>>>(
        x, x, sim, 4096,
        (long)NC * NPIX, (long)NC * NPIX, (long)NC * NC,
        NPIX, NPIX, NC, 4);
    // attn = softmax(sim/16 + rm)  (in place)
    softmax_kernel<<<2048, 256, 0, stream>>>(sim, rm);
    // attn2 = w_w @ attn  (NN, M=N=K=256; A not batched)
    gemm64<0><<<dim3(16, 32), 256, 0, stream>>>(
        w_w, sim, attn2, 256,
        0L, (long)NC * NC, (long)NC * NC,
        NC, NC, NC, 4);
    // out = attn2 @ value  (NN, M=256, N=4096, K=256)
    gemm64<0><<<dim3(256, 32), 256, 0, stream>>>(
        attn2, value, out, 256,
        (long)NC * NC, (long)NC * NPIX, (long)NC * NPIX,
        NC, NPIX, NPIX, 64);
}

// Round 2
// 974.460 us; speedup vs baseline: 3.2276x; 3.2276x over previous
//
#include <hip/hip_runtime.h>

// Problem: B=32, C=256, H=W=64, N=4096, R=16.
// out = (w_w @ softmax(x@x^T/16 + w1@w2^T)) @ conv3x3(x_mid, g_w)
// Round 2: conv3x3 -> bf16 MFMA implicit-GEMM (v_mfma_f32_32x32x16_bf16).

#define NB 32
#define NC 256
#define NPIX 4096   // 64*64

typedef __attribute__((ext_vector_type(8))) short short8;
typedef __attribute__((ext_vector_type(16))) float floatx16;

__device__ inline short f2bf(float f) {
    union { float f; unsigned u; } v; v.f = f;
    unsigned r = v.u + 0x7fffu + ((v.u >> 16) & 1u);   // RNE
    return (short)(r >> 16);
}

// ---------------- random_map = w1 @ w2^T  [256,256] ----------------
__global__ __launch_bounds__(256) void rm_kernel(const float* __restrict__ w1,
                                                 const float* __restrict__ w2,
                                                 float* __restrict__ rm) {
    int idx = blockIdx.x * 256 + threadIdx.x;
    int c = idx >> 8, d = idx & 255;
    float s = 0.f;
#pragma unroll
    for (int r = 0; r < 16; r++) s += w1[c * 16 + r] * w2[d * 16 + r];
    rm[idx] = s;
}

// ---------------- x_mid NCHW fp32 -> xt NHWC bf16 [b][h][w][ci] -------------
__global__ __launch_bounds__(256) void cvt_x_kernel(const float* __restrict__ x,
                                                    short* __restrict__ xt) {
    const int h = blockIdx.x;   // 64
    const int b = blockIdx.y;   // 32
    __shared__ short xls[64 * 256];   // [w][ci]
    const int tid = threadIdx.x;
    for (int i = tid; i < 4096; i += 256) {
        int ci = i >> 4, w4 = (i & 15) << 2;
        float4 v = *(const float4*)&x[(((size_t)(b * 256 + ci)) * 64 + h) * 64 + w4];
        xls[(w4 + 0) * 256 + ci] = f2bf(v.x);
        xls[(w4 + 1) * 256 + ci] = f2bf(v.y);
        xls[(w4 + 2) * 256 + ci] = f2bf(v.z);
        xls[(w4 + 3) * 256 + ci] = f2bf(v.w);
    }
    __syncthreads();
    uint4* dst = (uint4*)&xt[(((size_t)(b * 64 + h)) * 64) * 256];
    const uint4* src = (const uint4*)xls;
    for (int i = tid; i < 2048; i += 256) dst[i] = src[i];
}

// ------ g_w [co][ci][3][3] fp32 -> wt_l fragment-ordered bf16 ---------------
// wt_l[co_t(4)][ci_b(16)][tap(9)][ch(2)][ls(64)][j(8)]:
//   co = co_t*64 + ch*32 + (ls&31), ci = ci_b*16 + (ls>>5)*8 + j
__global__ __launch_bounds__(256) void cvt_w_kernel(const float* __restrict__ g_w,
                                                    short* __restrict__ wt) {
    int o = blockIdx.x * 256 + threadIdx.x;   // 73728 total (each = 8 bf16)
    if (o >= 73728) return;
    int co_t = o / 18432;
    int rem  = o - co_t * 18432;
    int ci_b = rem / 1152;
    int rem2 = rem - ci_b * 1152;
    int tap  = rem2 / 128;
    int rem3 = rem2 - tap * 128;
    int ch   = rem3 >> 6, ls = rem3 & 63;
    int co = co_t * 64 + ch * 32 + (ls & 31);
    int ci0 = ci_b * 16 + (ls >> 5) * 8;
    short8 v;
#pragma unroll
    for (int j = 0; j < 8; j++)
        v[j] = f2bf(g_w[((size_t)co * 256 + ci0 + j) * 9 + tap]);
    *(short8*)&wt[(size_t)o * 8] = v;
}

// ---------------- conv3x3 via MFMA: value[b][co][pix] fp32 ------------------
// Block: 64 co x 256 px (4 rows). 4 waves; wave wv -> output row h0+wv,
// 2 co-halves x 2 px-halves = 4 acc tiles of 32x32.
__global__ __launch_bounds__(256) void conv_mfma(const short* __restrict__ xt,
                                                 const short* __restrict__ wt,
                                                 float* __restrict__ value) {
    const int h0  = blockIdx.x * 4;
    const int cot = blockIdx.y;          // co0 = cot*64
    const int b   = blockIdx.z;
    __shared__ short ws[9 * 2 * 64 * 8];     // [tap][ch][ls][8]  18432 B
    __shared__ short xs[6 * 2 * 66 * 8];     // [r][kh2][wx][8]   12672 B
    const int tid = threadIdx.x;
    const int wv = tid >> 6, lane = tid & 63;
    const int kh2 = lane >> 5, ln = lane & 31;

    floatx16 acc00 = {}, acc01 = {}, acc10 = {}, acc11 = {};

    for (int cib = 0; cib < 16; ++cib) {
        __syncthreads();
        // stage weights: contiguous memcpy from fragment-ordered wt
        {
            const uint4* src = (const uint4*)&wt[((size_t)(cot * 16 + cib) * 1152) * 8];
            uint4* dst = (uint4*)ws;
            for (int i = tid; i < 1152; i += 256) dst[i] = src[i];
        }
        // stage input rows h0-1..h0+4, 16 ci, with zero halos
        {
            uint4* dst = (uint4*)xs;
            for (int i = tid; i < 792; i += 256) {
                if (i < 768) {
                    int r = i >> 7, rem = i & 127, w = rem >> 1, half = rem & 1;
                    int hin = h0 - 1 + r;
                    uint4 v = make_uint4(0, 0, 0, 0);
                    if ((unsigned)hin < 64u)
                        v = *(const uint4*)&xt[(((size_t)(b * 64 + hin)) * 64 + w) * 256 + cib * 16 + half * 8];
                    dst[(r * 2 + half) * 66 + 1 + w] = v;
                } else {
                    int j = i - 768;                 // 24 halo slots
                    int r = j >> 2, half = (j >> 1) & 1, side = j & 1;
                    dst[(r * 2 + half) * 66 + side * 65] = make_uint4(0, 0, 0, 0);
                }
            }
        }
        __syncthreads();

#pragma unroll
        for (int tap = 0; tap < 9; ++tap) {
            const int kh = tap / 3, kw = tap - kh * 3;
            const int r = wv + kh;
            short8 a0 = *(const short8*)&ws[((tap * 2 + 0) * 64 + lane) * 8];
            short8 a1 = *(const short8*)&ws[((tap * 2 + 1) * 64 + lane) * 8];
            short8 b0 = *(const short8*)&xs[(((r * 2 + kh2) * 66) + kw + ln) * 8];
            short8 b1 = *(const short8*)&xs[(((r * 2 + kh2) * 66) + kw + 32 + ln) * 8];
            acc00 = __builtin_amdgcn_mfma_f32_32x32x16_bf16(a0, b0, acc00, 0, 0, 0);
            acc01 = __builtin_amdgcn_mfma_f32_32x32x16_bf16(a0, b1, acc01, 0, 0, 0);
            acc10 = __builtin_amdgcn_mfma_f32_32x32x16_bf16(a1, b0, acc10, 0, 0, 0);
            acc11 = __builtin_amdgcn_mfma_f32_32x32x16_bf16(a1, b1, acc11, 0, 0, 0);
        }
    }

    // epilogue: C/D layout col=lane&31, row=(reg&3)+8*(reg>>2)+4*(lane>>5)
    const int h_out = h0 + wv;
#pragma unroll
    for (int reg = 0; reg < 16; ++reg) {
        int m = (reg & 3) + 8 * (reg >> 2) + 4 * kh2;
        size_t base0 = ((size_t)(b * 256 + cot * 64 + m)) * 4096 + h_out * 64;
        size_t base1 = ((size_t)(b * 256 + cot * 64 + 32 + m)) * 4096 + h_out * 64;
        value[base0 + ln]      = acc00[reg];
        value[base0 + 32 + ln] = acc01[reg];
        value[base1 + ln]      = acc10[reg];
        value[base1 + 32 + ln] = acc11[reg];
    }
}

// ---------------- generic batched fp32 GEMM, 64x64 tile, 4x4/thread ----------
template <int BT>
__global__ __launch_bounds__(256) void gemm64(const float* __restrict__ A,
                                              const float* __restrict__ B,
                                              float* __restrict__ C, int K,
                                              long sA, long sB, long sC,
                                              int ldA, int ldB, int ldC, int tilesN) {
    const int m0 = (blockIdx.x / tilesN) * 64;
    const int n0 = (blockIdx.x % tilesN) * 64;
    A += (size_t)blockIdx.y * sA;
    B += (size_t)blockIdx.y * sB;
    C += (size_t)blockIdx.y * sC;
    __shared__ float As[16][68], Bs[16][68];
    const int tid = threadIdx.x;
    const int tx = tid & 15, ty = tid >> 4;
    const int mm = tid >> 2, kk4 = (tid & 3) * 4;
    float acc[4][4] = {};

    for (int k0 = 0; k0 < K; k0 += 16) {
        __syncthreads();
        {
            float4 a = *(const float4*)&A[(size_t)(m0 + mm) * ldA + k0 + kk4];
            As[kk4 + 0][mm] = a.x; As[kk4 + 1][mm] = a.y;
            As[kk4 + 2][mm] = a.z; As[kk4 + 3][mm] = a.w;
        }
        if (BT) {
            float4 bv = *(const float4*)&B[(size_t)(n0 + mm) * ldB + k0 + kk4];
            Bs[kk4 + 0][mm] = bv.x; Bs[kk4 + 1][mm] = bv.y;
            Bs[kk4 + 2][mm] = bv.z; Bs[kk4 + 3][mm] = bv.w;
        } else {
            int bk = tid >> 4, bn = (tid & 15) * 4;
            *(float4*)&Bs[bk][bn] = *(const float4*)&B[(size_t)(k0 + bk) * ldB + n0 + bn];
        }
        __syncthreads();
#pragma unroll
        for (int kk = 0; kk < 16; kk++) {
            float4 a = *(float4*)&As[kk][ty * 4];
            float4 bv = *(float4*)&Bs[kk][tx * 4];
            float av[4] = {a.x, a.y, a.z, a.w};
            float bb[4] = {bv.x, bv.y, bv.z, bv.w};
#pragma unroll
            for (int i = 0; i < 4; i++)
#pragma unroll
                for (int j = 0; j < 4; j++) acc[i][j] += av[i] * bb[j];
        }
    }
#pragma unroll
    for (int i = 0; i < 4; i++) {
        float4 o = make_float4(acc[i][0], acc[i][1], acc[i][2], acc[i][3]);
        *(float4*)&C[(size_t)(m0 + ty * 4 + i) * ldC + n0 + tx * 4] = o;
    }
}

// ---------------- softmax over last dim (256) with scale + bias -------------
__global__ __launch_bounds__(256) void softmax_kernel(float* __restrict__ sim,
                                                      const float* __restrict__ rm) {
    int row  = blockIdx.x * 4 + (threadIdx.x >> 6);
    int lane = threadIdx.x & 63;
    int c = row & 255;
    float4 v = *(float4*)&sim[(size_t)row * 256 + lane * 4];
    const float4 bias = *(const float4*)&rm[c * 256 + lane * 4];
    v.x = v.x * 0.0625f + bias.x;
    v.y = v.y * 0.0625f + bias.y;
    v.z = v.z * 0.0625f + bias.z;
    v.w = v.w * 0.0625f + bias.w;
    float m = fmaxf(fmaxf(v.x, v.y), fmaxf(v.z, v.w));
#pragma unroll
    for (int off = 32; off > 0; off >>= 1) m = fmaxf(m, __shfl_xor(m, off, 64));
    float e0 = __expf(v.x - m), e1 = __expf(v.y - m);
    float e2 = __expf(v.z - m), e3 = __expf(v.w - m);
    float s = e0 + e1 + e2 + e3;
#pragma unroll
    for (int off = 32; off > 0; off >>= 1) s += __shfl_xor(s, off, 64);
    float inv = 1.f / s;
    float4 o = make_float4(e0 * inv, e1 * inv, e2 * inv, e3 * inv);
    *(float4*)&sim[(size_t)row * 256 + lane * 4] = o;
}

extern "C" void kernel_launch(void* const* d_in, const int* in_sizes, int n_in,
                              void* d_out, int out_size, void* d_ws, size_t ws_size,
                              hipStream_t stream) {
    const float* x     = (const float*)d_in[0];
    const float* x_mid = (const float*)d_in[1];
    const float* g_w   = (const float*)d_in[2];
    const float* w_w   = (const float*)d_in[3];
    const float* w1    = (const float*)d_in[4];
    const float* w2    = (const float*)d_in[5];
    float* out = (float*)d_out;

    char* ws = (char*)d_ws;
    float* value = (float*)ws;                                   // 134.2 MB
    float* sim   = (float*)(ws + (size_t)NB * NC * NPIX * 4);    // 8 MB
    float* attn2 = sim + (size_t)NB * NC * NC;                   // 8 MB
    float* rm    = attn2 + (size_t)NB * NC * NC;                 // 0.25 MB
    short* xt    = (short*)(rm + NC * NC);                       // 67.1 MB
    short* wt    = xt + (size_t)NB * 64 * 64 * NC;               // 1.18 MB

    cvt_w_kernel<<<288, 256, 0, stream>>>(g_w, wt);
    cvt_x_kernel<<<dim3(64, 32), 256, 0, stream>>>(x_mid, xt);
    rm_kernel<<<256, 256, 0, stream>>>(w1, w2, rm);
    conv_mfma<<<dim3(16, 4, 32), 256, 0, stream>>>(xt, wt, value);
    // sim = x @ x^T   (NT GEMM, M=N=256, K=4096)
    gemm64<1><<<dim3(16, 32), 256, 0, stream>>>(
        x, x, sim, 4096,
        (long)NC * NPIX, (long)NC * NPIX, (long)NC * NC,
        NPIX, NPIX, NC, 4);
    softmax_kernel<<<2048, 256, 0, stream>>>(sim, rm);
    // attn2 = w_w @ attn  (NN, M=N=K=256; A not batched)
    gemm64<0><<<dim3(16, 32), 256, 0, stream>>>(
        w_w, sim, attn2, 256,
        0L, (long)NC * NC, (long)NC * NC,
        NC, NC, NC, 4);
    // out = attn2 @ value  (NN, M=256, N=4096, K=256)
    gemm64<0><<<dim3(256, 32), 256, 0, stream>>>(
        attn2, value, out, 256,
        (long)NC * NC, (long)NC * NPIX, (long)NC * NPIX,
        NC, NPIX, NPIX, 64);
}

// Round 3
// 725.937 us; speedup vs baseline: 4.3325x; 1.3423x over previous
//
#include <hip/hip_runtime.h>

// Problem: B=32, C=256, H=W=64, N=4096, R=16.
// out = (w_w @ softmax(x@x^T/16 + w1@w2^T)) @ conv3x3(x_mid, g_w)
// Round 3: sim and out GEMMs -> bf16 MFMA with direct-from-global K-contiguous
// fragments; conv operands swapped so value is written as [px][co] bf16.

#define NB 32
#define NC 256
#define NPIX 4096   // 64*64

typedef __attribute__((ext_vector_type(8))) short short8;
typedef __attribute__((ext_vector_type(16))) float floatx16;

__device__ inline short f2bf(float f) {
    union { float f; unsigned u; } v; v.f = f;
    unsigned r = v.u + 0x7fffu + ((v.u >> 16) & 1u);   // RNE
    return (short)(r >> 16);
}

// ---------------- random_map = w1 @ w2^T  [256,256] ----------------
__global__ __launch_bounds__(256) void rm_kernel(const float* __restrict__ w1,
                                                 const float* __restrict__ w2,
                                                 float* __restrict__ rm) {
    int idx = blockIdx.x * 256 + threadIdx.x;
    int c = idx >> 8, d = idx & 255;
    float s = 0.f;
#pragma unroll
    for (int r = 0; r < 16; r++) s += w1[c * 16 + r] * w2[d * 16 + r];
    rm[idx] = s;
}

// ---------------- generic fp32 -> bf16 (same layout), 8 elems/thread --------
__global__ __launch_bounds__(256) void cvt_bf16_kernel(const float* __restrict__ in,
                                                       short* __restrict__ out) {
    size_t i = ((size_t)blockIdx.x * 256 + threadIdx.x) * 8;
    float4 v0 = *(const float4*)&in[i];
    float4 v1 = *(const float4*)&in[i + 4];
    short8 s;
    s[0] = f2bf(v0.x); s[1] = f2bf(v0.y); s[2] = f2bf(v0.z); s[3] = f2bf(v0.w);
    s[4] = f2bf(v1.x); s[5] = f2bf(v1.y); s[6] = f2bf(v1.z); s[7] = f2bf(v1.w);
    *(short8*)&out[i] = s;
}

// ---------------- x_mid NCHW fp32 -> xt NHWC bf16 [b][h][w][ci] -------------
__global__ __launch_bounds__(256) void cvt_x_kernel(const float* __restrict__ x,
                                                    short* __restrict__ xt) {
    const int h = blockIdx.x;   // 64
    const int b = blockIdx.y;   // 32
    __shared__ short xls[64 * 256];   // [w][ci]
    const int tid = threadIdx.x;
    for (int i = tid; i < 4096; i += 256) {
        int ci = i >> 4, w4 = (i & 15) << 2;
        float4 v = *(const float4*)&x[(((size_t)(b * 256 + ci)) * 64 + h) * 64 + w4];
        xls[(w4 + 0) * 256 + ci] = f2bf(v.x);
        xls[(w4 + 1) * 256 + ci] = f2bf(v.y);
        xls[(w4 + 2) * 256 + ci] = f2bf(v.z);
        xls[(w4 + 3) * 256 + ci] = f2bf(v.w);
    }
    __syncthreads();
    uint4* dst = (uint4*)&xt[(((size_t)(b * 64 + h)) * 64) * 256];
    const uint4* src = (const uint4*)xls;
    for (int i = tid; i < 2048; i += 256) dst[i] = src[i];
}

// ------ g_w [co][ci][3][3] fp32 -> wt fragment-ordered bf16 -----------------
// wt[co_t(4)][ci_b(16)][tap(9)][ch(2)][ls(64)][j(8)]:
//   co = co_t*64 + ch*32 + (ls&31), ci = ci_b*16 + (ls>>5)*8 + j
__global__ __launch_bounds__(256) void cvt_w_kernel(const float* __restrict__ g_w,
                                                    short* __restrict__ wt) {
    int o = blockIdx.x * 256 + threadIdx.x;   // 73728 total (each = 8 bf16)
    if (o >= 73728) return;
    int co_t = o / 18432;
    int rem  = o - co_t * 18432;
    int ci_b = rem / 1152;
    int rem2 = rem - ci_b * 1152;
    int tap  = rem2 / 128;
    int rem3 = rem2 - tap * 128;
    int ch   = rem3 >> 6, ls = rem3 & 63;
    int co = co_t * 64 + ch * 32 + (ls & 31);
    int ci0 = ci_b * 16 + (ls >> 5) * 8;
    short8 v;
#pragma unroll
    for (int j = 0; j < 8; j++)
        v[j] = f2bf(g_w[((size_t)co * 256 + ci0 + j) * 9 + tap]);
    *(short8*)&wt[(size_t)o * 8] = v;
}

// ---------------- conv3x3 via MFMA -> value_t[b][px][co] bf16 ---------------
// A-operand = x patches (m=px), B-operand = weights (n=co); C[px][co].
__global__ __launch_bounds__(256) void conv_mfma(const short* __restrict__ xt,
                                                 const short* __restrict__ wt,
                                                 short* __restrict__ value_t) {
    const int h0  = blockIdx.x * 4;
    const int cot = blockIdx.y;          // co0 = cot*64
    const int b   = blockIdx.z;
    __shared__ short ws[9 * 2 * 64 * 8];     // [tap][ch][ls][8]  18432 B
    __shared__ short xs[6 * 2 * 66 * 8];     // [r][kh2][wx][8]   12672 B
    const int tid = threadIdx.x;
    const int wv = tid >> 6, lane = tid & 63;
    const int kh2 = lane >> 5, ln = lane & 31;

    floatx16 acc00 = {}, acc01 = {}, acc10 = {}, acc11 = {};   // [pxh][coh]

    for (int cib = 0; cib < 16; ++cib) {
        __syncthreads();
        {
            const uint4* src = (const uint4*)&wt[((size_t)(cot * 16 + cib) * 1152) * 8];
            uint4* dst = (uint4*)ws;
            for (int i = tid; i < 1152; i += 256) dst[i] = src[i];
        }
        {
            uint4* dst = (uint4*)xs;
            for (int i = tid; i < 792; i += 256) {
                if (i < 768) {
                    int r = i >> 7, rem = i & 127, w = rem >> 1, half = rem & 1;
                    int hin = h0 - 1 + r;
                    uint4 v = make_uint4(0, 0, 0, 0);
                    if ((unsigned)hin < 64u)
                        v = *(const uint4*)&xt[(((size_t)(b * 64 + hin)) * 64 + w) * 256 + cib * 16 + half * 8];
                    dst[(r * 2 + half) * 66 + 1 + w] = v;
                } else {
                    int j = i - 768;
                    int r = j >> 2, half = (j >> 1) & 1, side = j & 1;
                    dst[(r * 2 + half) * 66 + side * 65] = make_uint4(0, 0, 0, 0);
                }
            }
        }
        __syncthreads();

#pragma unroll
        for (int tap = 0; tap < 9; ++tap) {
            const int kh = tap / 3, kw = tap - kh * 3;
            const int r = wv + kh;
            short8 wf0 = *(const short8*)&ws[((tap * 2 + 0) * 64 + lane) * 8];
            short8 wf1 = *(const short8*)&ws[((tap * 2 + 1) * 64 + lane) * 8];
            short8 xf0 = *(const short8*)&xs[(((r * 2 + kh2) * 66) + kw + ln) * 8];
            short8 xf1 = *(const short8*)&xs[(((r * 2 + kh2) * 66) + kw + 32 + ln) * 8];
            acc00 = __builtin_amdgcn_mfma_f32_32x32x16_bf16(xf0, wf0, acc00, 0, 0, 0);
            acc01 = __builtin_amdgcn_mfma_f32_32x32x16_bf16(xf0, wf1, acc01, 0, 0, 0);
            acc10 = __builtin_amdgcn_mfma_f32_32x32x16_bf16(xf1, wf0, acc10, 0, 0, 0);
            acc11 = __builtin_amdgcn_mfma_f32_32x32x16_bf16(xf1, wf1, acc11, 0, 0, 0);
        }
    }

    // C/D: col(lane&31)=co, row=(reg&3)+8*(reg>>2)+4*kh2 = px within 32-tile
    const int h_out = h0 + wv;
    short* vt = value_t + ((size_t)(b * 4096 + h_out * 64)) * 256 + cot * 64;
#pragma unroll
    for (int reg = 0; reg < 16; ++reg) {
        int m = (reg & 3) + 8 * (reg >> 2) + 4 * kh2;
        vt[(size_t)m * 256 + ln]             = f2bf(acc00[reg]);
        vt[(size_t)m * 256 + 32 + ln]        = f2bf(acc01[reg]);
        vt[(size_t)(m + 32) * 256 + ln]      = f2bf(acc10[reg]);
        vt[(size_t)(m + 32) * 256 + 32 + ln] = f2bf(acc11[reg]);
    }
}

// ------------- bf16 NT-GEMM: C[M,N]fp32 = A[M,K] @ B[N,K]^T -----------------
// Fragments loaded directly from global (both operands K-contiguous).
// Block 128 thr = 2 waves; block tile 64m x 128n; wave: 32m x 4 n-tiles.
__global__ __launch_bounds__(128) void gemm_nt_bf16(const short* __restrict__ A,
                                                    const short* __restrict__ B,
                                                    float* __restrict__ C, int K,
                                                    long sA, long sB, long sC,
                                                    int ldc, int tilesN) {
    const int mt = blockIdx.x / tilesN, nt = blockIdx.x % tilesN;
    A += (size_t)blockIdx.y * sA;
    B += (size_t)blockIdx.y * sB;
    C += (size_t)blockIdx.y * sC;
    const int wv = threadIdx.x >> 6, l = threadIdx.x & 63;
    const int ln = l & 31, kh = l >> 5;
    const short* arow = A + (size_t)(mt * 64 + wv * 32 + ln) * K + kh * 8;
    const short* brow = B + (size_t)(nt * 128 + ln) * K + kh * 8;
    floatx16 acc0 = {}, acc1 = {}, acc2 = {}, acc3 = {};
#pragma unroll 2
    for (int k0 = 0; k0 < K; k0 += 16) {
        short8 a  = *(const short8*)&arow[k0];
        short8 b0 = *(const short8*)&brow[k0];
        short8 b1 = *(const short8*)&brow[(size_t)32 * K + k0];
        short8 b2 = *(const short8*)&brow[(size_t)64 * K + k0];
        short8 b3 = *(const short8*)&brow[(size_t)96 * K + k0];
        acc0 = __builtin_amdgcn_mfma_f32_32x32x16_bf16(a, b0, acc0, 0, 0, 0);
        acc1 = __builtin_amdgcn_mfma_f32_32x32x16_bf16(a, b1, acc1, 0, 0, 0);
        acc2 = __builtin_amdgcn_mfma_f32_32x32x16_bf16(a, b2, acc2, 0, 0, 0);
        acc3 = __builtin_amdgcn_mfma_f32_32x32x16_bf16(a, b3, acc3, 0, 0, 0);
    }
    const int n0 = nt * 128;
#pragma unroll
    for (int reg = 0; reg < 16; ++reg) {
        int m = mt * 64 + wv * 32 + (reg & 3) + 8 * (reg >> 2) + 4 * kh;
        float* crow = C + (size_t)m * ldc + n0 + ln;
        crow[0]  = acc0[reg];
        crow[32] = acc1[reg];
        crow[64] = acc2[reg];
        crow[96] = acc3[reg];
    }
}

// ---------------- fp32 GEMM 64x64 (kept for tiny attn2), opt bf16 out -------
template <int BT, int OB>
__global__ __launch_bounds__(256) void gemm64(const float* __restrict__ A,
                                              const float* __restrict__ B,
                                              float* __restrict__ C, int K,
                                              long sA, long sB, long sC,
                                              int ldA, int ldB, int ldC, int tilesN) {
    const int m0 = (blockIdx.x / tilesN) * 64;
    const int n0 = (blockIdx.x % tilesN) * 64;
    A += (size_t)blockIdx.y * sA;
    B += (size_t)blockIdx.y * sB;
    const size_t coff = (size_t)blockIdx.y * sC;
    __shared__ float As[16][68], Bs[16][68];
    const int tid = threadIdx.x;
    const int tx = tid & 15, ty = tid >> 4;
    const int mm = tid >> 2, kk4 = (tid & 3) * 4;
    float acc[4][4] = {};

    for (int k0 = 0; k0 < K; k0 += 16) {
        __syncthreads();
        {
            float4 a = *(const float4*)&A[(size_t)(m0 + mm) * ldA + k0 + kk4];
            As[kk4 + 0][mm] = a.x; As[kk4 + 1][mm] = a.y;
            As[kk4 + 2][mm] = a.z; As[kk4 + 3][mm] = a.w;
        }
        if (BT) {
            float4 bv = *(const float4*)&B[(size_t)(n0 + mm) * ldB + k0 + kk4];
            Bs[kk4 + 0][mm] = bv.x; Bs[kk4 + 1][mm] = bv.y;
            Bs[kk4 + 2][mm] = bv.z; Bs[kk4 + 3][mm] = bv.w;
        } else {
            int bk = tid >> 4, bn = (tid & 15) * 4;
            *(float4*)&Bs[bk][bn] = *(const float4*)&B[(size_t)(k0 + bk) * ldB + n0 + bn];
        }
        __syncthreads();
#pragma unroll
        for (int kk = 0; kk < 16; kk++) {
            float4 a = *(float4*)&As[kk][ty * 4];
            float4 bv = *(float4*)&Bs[kk][tx * 4];
            float av[4] = {a.x, a.y, a.z, a.w};
            float bb[4] = {bv.x, bv.y, bv.z, bv.w};
#pragma unroll
            for (int i = 0; i < 4; i++)
#pragma unroll
                for (int j = 0; j < 4; j++) acc[i][j] += av[i] * bb[j];
        }
    }
#pragma unroll
    for (int i = 0; i < 4; i++) {
        if (OB) {
            short* Cs = (short*)C + coff;
            short4 o;
            o.x = f2bf(acc[i][0]); o.y = f2bf(acc[i][1]);
            o.z = f2bf(acc[i][2]); o.w = f2bf(acc[i][3]);
            *(short4*)&Cs[(size_t)(m0 + ty * 4 + i) * ldC + n0 + tx * 4] = o;
        } else {
            float* Cf = (float*)C + coff;
            float4 o = make_float4(acc[i][0], acc[i][1], acc[i][2], acc[i][3]);
            *(float4*)&Cf[(size_t)(m0 + ty * 4 + i) * ldC + n0 + tx * 4] = o;
        }
    }
}

// ---------------- softmax over last dim (256) with scale + bias -------------
__global__ __launch_bounds__(256) void softmax_kernel(float* __restrict__ sim,
                                                      const float* __restrict__ rm) {
    int row  = blockIdx.x * 4 + (threadIdx.x >> 6);
    int lane = threadIdx.x & 63;
    int c = row & 255;
    float4 v = *(float4*)&sim[(size_t)row * 256 + lane * 4];
    const float4 bias = *(const float4*)&rm[c * 256 + lane * 4];
    v.x = v.x * 0.0625f + bias.x;
    v.y = v.y * 0.0625f + bias.y;
    v.z = v.z * 0.0625f + bias.z;
    v.w = v.w * 0.0625f + bias.w;
    float m = fmaxf(fmaxf(v.x, v.y), fmaxf(v.z, v.w));
#pragma unroll
    for (int off = 32; off > 0; off >>= 1) m = fmaxf(m, __shfl_xor(m, off, 64));
    float e0 = __expf(v.x - m), e1 = __expf(v.y - m);
    float e2 = __expf(v.z - m), e3 = __expf(v.w - m);
    float s = e0 + e1 + e2 + e3;
#pragma unroll
    for (int off = 32; off > 0; off >>= 1) s += __shfl_xor(s, off, 64);
    float inv = 1.f / s;
    float4 o = make_float4(e0 * inv, e1 * inv, e2 * inv, e3 * inv);
    *(float4*)&sim[(size_t)row * 256 + lane * 4] = o;
}

extern "C" void kernel_launch(void* const* d_in, const int* in_sizes, int n_in,
                              void* d_out, int out_size, void* d_ws, size_t ws_size,
                              hipStream_t stream) {
    const float* x     = (const float*)d_in[0];
    const float* x_mid = (const float*)d_in[1];
    const float* g_w   = (const float*)d_in[2];
    const float* w_w   = (const float*)d_in[3];
    const float* w1    = (const float*)d_in[4];
    const float* w2    = (const float*)d_in[5];
    float* out = (float*)d_out;

    char* ws = (char*)d_ws;
    short* value_t = (short*)ws;                                   // 67.1 MB [b][px][co]
    float* sim     = (float*)(ws + (size_t)NB * NPIX * NC * 2);    // 8.4 MB
    short* attn2_b = (short*)(sim + (size_t)NB * NC * NC);         // 4.2 MB [b][co][d]
    float* rm      = (float*)(attn2_b + (size_t)NB * NC * NC);     // 0.26 MB
    short* xt      = (short*)(rm + NC * NC);                       // 67.1 MB
    short* xb      = xt + (size_t)NB * NPIX * NC;                  // 67.1 MB
    short* wt      = xb + (size_t)NB * NC * NPIX;                  // 1.18 MB

    cvt_w_kernel<<<288, 256, 0, stream>>>(g_w, wt);
    cvt_x_kernel<<<dim3(64, 32), 256, 0, stream>>>(x_mid, xt);
    cvt_bf16_kernel<<<16384, 256, 0, stream>>>(x, xb);
    rm_kernel<<<256, 256, 0, stream>>>(w1, w2, rm);
    // value_t[b][px][co] = conv3x3(x_mid, g_w)
    conv_mfma<<<dim3(16, 4, 32), 256, 0, stream>>>(xt, wt, value_t);
    // sim = xb @ xb^T   (M=N=256, K=4096)
    gemm_nt_bf16<<<dim3(8, 32), 128, 0, stream>>>(
        xb, xb, sim, 4096,
        (long)NC * NPIX, (long)NC * NPIX, (long)NC * NC, NC, 2);
    softmax_kernel<<<2048, 256, 0, stream>>>(sim, rm);
    // attn2_b = bf16(w_w @ attn)  (M=N=K=256; A not batched)
    gemm64<0, 1><<<dim3(16, 32), 256, 0, stream>>>(
        w_w, sim, (float*)attn2_b, 256,
        0L, (long)NC * NC, (long)NC * NC,
        NC, NC, NC, 4);
    // out[b][co][px] = attn2_b @ value_t^T  (M=256, N=4096, K=256)
    gemm_nt_bf16<<<dim3(128, 32), 128, 0, stream>>>(
        attn2_b, value_t, out, 256,
        (long)NC * NC, (long)NPIX * NC, (long)NC * NPIX, NPIX, 32);
}